// Round 15
// baseline (181.644 us; speedup 1.0000x reference)
//
#include <hip/hip_runtime.h>
#include <hip/hip_bf16.h>

#define BB 2
#define TT 2048
#define CC 1024
#define HH 16
#define HDD 64

typedef __attribute__((ext_vector_type(8))) short bf16x8;
typedef __attribute__((ext_vector_type(4))) float f32x4;

static __device__ __forceinline__ unsigned short f2bf(float f) {
  union { float f; unsigned u; } v; v.f = f;
  unsigned r = v.u + 0x7fffu + ((v.u >> 16) & 1u);  // RNE
  return (unsigned short)(r >> 16);
}

static __device__ __forceinline__ unsigned fbits(float f) {
  union { float f; unsigned u; } v; v.f = f; return v.u;
}

// pack two fp32 -> two bf16 (truncate) in ONE v_perm_b32
static __device__ __forceinline__ unsigned pk_trunc(float lo, float hi) {
  return __builtin_amdgcn_perm(fbits(hi), fbits(lo), 0x07060302u);
}

// raw v_exp_f32 (args bounded; skips OCML range/subnormal fixup)
static __device__ __forceinline__ float fexp2(float x) {
#if __has_builtin(__builtin_amdgcn_exp2f)
  return __builtin_amdgcn_exp2f(x);
#else
  return exp2f(x);
#endif
}

static __device__ __forceinline__ void gload_lds16(const unsigned short* g, unsigned short* l) {
  __builtin_amdgcn_global_load_lds((const __attribute__((address_space(1))) void*)g,
                                   (__attribute__((address_space(3))) void*)l, 16, 0, 0);
}

// fp32 -> bf16 for x (4M), Wq,Wk,Wv,Wp (1M each), into contiguous dst.
__global__ __launch_bounds__(256) void convert_all(
    const float* __restrict__ x, const float* __restrict__ Wq,
    const float* __restrict__ Wk, const float* __restrict__ Wv,
    const float* __restrict__ Wp, unsigned short* __restrict__ dst)
{
  const size_t M4 = 4194304, M1 = 1048576;
  const size_t e = ((size_t)blockIdx.x * 256 + threadIdx.x) * 8;
  const float* src; size_t off;
  if (e < M4)            { src = x;  off = e; }
  else if (e < M4 + M1)  { src = Wq; off = e - M4; }
  else if (e < M4 + 2*M1){ src = Wk; off = e - M4 - M1; }
  else if (e < M4 + 3*M1){ src = Wv; off = e - M4 - 2*M1; }
  else                   { src = Wp; off = e - M4 - 3*M1; }
  float4 a = *(const float4*)(src + off);
  float4 c = *(const float4*)(src + off + 4);
  unsigned short buf[8] = {f2bf(a.x), f2bf(a.y), f2bf(a.z), f2bf(a.w),
                           f2bf(c.x), f2bf(c.y), f2bf(c.z), f2bf(c.w)};
  *(uint4*)(dst + e) = *(const uint4*)buf;
}

// ---------------------------------------------------------------------------
// R27: single change vs R26 — attn K/V staging via global_load_lds with
// pre-swizzled SOURCE (the GEMM-proven m173/R13 pattern), replacing the
// reg round-trip (2 global loads + 2 VGPR uint4 + 2 LDS stores / thread /
// iter). LDS dest linear (+t*8); source chunk = (t&7)^(sr&7) -> phys chunk c
// holds logical c^(row&7): IDENTICAL final layout to R26 (XOR involution),
// read side untouched. Sync = R13 ledger: stage kt+1 into buf^1 after kt's
// barrier (WAR: buf^1 readers done pre-barrier); vmcnt(0) at top of kt+1
// (full iteration of compute cover); one barrier per iter (unchanged).
// QKV gemm (R17), proj (R22), convert unchanged.
// ---------------------------------------------------------------------------

// bf16 MFMA GEMM for fused QKV. grid (32,24), 256 threads. [R17 exact]
__global__ __launch_bounds__(256) void gemm_mfma(
    const unsigned short* __restrict__ A, const unsigned short* __restrict__ W,
    const float* __restrict__ b0, const float* __restrict__ b1, const float* __restrict__ b2,
    unsigned short* __restrict__ oQ, unsigned short* __restrict__ oK,
    unsigned short* __restrict__ oVt)
{
  __shared__ unsigned short As[3][128][32];
  __shared__ unsigned short Bs[3][128][32];
  const int t = threadIdx.x;
  const int wv = __builtin_amdgcn_readfirstlane(t >> 6);
  const int ln = t & 63;
  const int l16 = ln & 15;
  const int quad = ln >> 4;
  const int mBase = blockIdx.x * 128;
  const int nBase = blockIdx.y * 128;
  const int wm = (wv >> 1) * 64, wn = (wv & 1) * 64;

  f32x4 acc[4][4];
#pragma unroll
  for (int i = 0; i < 4; i++)
#pragma unroll
    for (int j = 0; j < 4; j++) acc[i][j] = (f32x4){0.f, 0.f, 0.f, 0.f};

  const int rloc = t >> 2;
  const int csrc = ((t & 3) ^ ((t >> 3) & 3)) * 8;
  const unsigned short* gA = A + (size_t)(mBase + rloc) * CC + csrc;
  const unsigned short* gB = W + (size_t)(nBase + rloc) * CC + csrc;
  const int sw = (quad ^ ((l16 >> 1) & 3)) * 8;

#define STAGE(b, kt)                                                       \
  do {                                                                     \
    const size_t ko = (size_t)(kt) * 32;                                   \
    gload_lds16(gA + ko,           &As[b][0][0] + t * 8);                  \
    gload_lds16(gA + ko + 64 * CC, &As[b][64][0] + t * 8);                 \
    gload_lds16(gB + ko,           &Bs[b][0][0] + t * 8);                  \
    gload_lds16(gB + ko + 64 * CC, &Bs[b][64][0] + t * 8);                 \
  } while (0)

  STAGE(0, 0);
  STAGE(1, 1);
  int cur = 0, nxt2 = 2;
  for (int kt = 0; kt < 32; ++kt) {
    if (kt < 30) {
      STAGE(nxt2, kt + 2);
      asm volatile("s_waitcnt vmcnt(8)" ::: "memory");
    } else if (kt == 30) {
      asm volatile("s_waitcnt vmcnt(4)" ::: "memory");
    } else {
      asm volatile("s_waitcnt vmcnt(0)" ::: "memory");
    }
    __builtin_amdgcn_s_barrier();
    asm volatile("" ::: "memory");
    bf16x8 af[4], bfr[4];
#pragma unroll
    for (int i = 0; i < 4; ++i) af[i] = *(const bf16x8*)&As[cur][wm + i * 16 + l16][sw];
#pragma unroll
    for (int j = 0; j < 4; ++j) bfr[j] = *(const bf16x8*)&Bs[cur][wn + j * 16 + l16][sw];
    __builtin_amdgcn_s_setprio(1);
#pragma unroll
    for (int i = 0; i < 4; ++i)
#pragma unroll
      for (int j = 0; j < 4; ++j)
        acc[i][j] = __builtin_amdgcn_mfma_f32_16x16x32_bf16(af[i], bfr[j], acc[i][j], 0, 0, 0);
    __builtin_amdgcn_s_setprio(0);
    asm volatile("" ::: "memory");
    __builtin_amdgcn_s_barrier();
    asm volatile("" ::: "memory");
    cur = (cur == 2) ? 0 : cur + 1;
    nxt2 = (nxt2 == 2) ? 0 : nxt2 + 1;
  }
#undef STAGE

  const int which = nBase >> 10;
  const float* bias = which == 0 ? b0 : (which == 1 ? b1 : b2);
  unsigned short* dst = which == 0 ? oQ : (which == 1 ? oK : oVt);
  const float scl = which == 0 ? 0.1803368801f : 1.0f;  // 0.125*log2(e) on Q
#pragma unroll
  for (int i = 0; i < 4; i++)
#pragma unroll
    for (int r = 0; r < 4; r++) {
      const int m = mBase + wm + i * 16 + quad * 4 + r;
      const int b = m >> 11, tp = m & 2047;
#pragma unroll
      for (int j = 0; j < 4; j++) {
        const int n = nBase + wn + j * 16 + l16;
        const int nl = n & 1023, h = nl >> 6, d = nl & 63;
        const unsigned short v = f2bf((acc[i][j][r] + bias[nl]) * scl);
        if (which < 2) dst[((size_t)(b * HH + h) * TT + tp) * HDD + d] = v;
        else           dst[((size_t)(b * HH + h) * HDD + d) * TT + tp] = v;
      }
    }
}

// Output projection: 64x128 tile, BK=64 dbuf (16 MFMA/interval), vmcnt(6),
// 256 threads, grid (64,8) = 512 blocks = 2 blocks/CU. [R22 exact]
__global__ __launch_bounds__(256) void gemm_proj(
    const unsigned short* __restrict__ A, const unsigned short* __restrict__ W,
    const float* __restrict__ bias, float* __restrict__ out)
{
  __shared__ unsigned short As[2][64][64];
  __shared__ unsigned short Bs[2][128][64];
  const int t = threadIdx.x;
  const int wv = __builtin_amdgcn_readfirstlane(t >> 6);
  const int ln = t & 63;
  const int l16 = ln & 15;
  const int quad = ln >> 4;
  const int mBase = blockIdx.x * 64;
  const int nBase = blockIdx.y * 128;
  const int wm = (wv >> 1) * 32, wn = (wv & 1) * 64;

  f32x4 acc[2][4];
#pragma unroll
  for (int i = 0; i < 2; i++)
#pragma unroll
    for (int j = 0; j < 4; j++) acc[i][j] = (f32x4){0.f, 0.f, 0.f, 0.f};

  const int srow = t >> 3;                         // 0..31
  const int schunk = ((t & 7) ^ (srow & 7)) * 8;
  const unsigned short* gA = A + (size_t)(mBase + srow) * CC + schunk;
  const unsigned short* gB = W + (size_t)(nBase + srow) * CC + schunk;
  const int sw0 = ((0 + quad) ^ (l16 & 7)) * 8;
  const int sw1 = ((4 + quad) ^ (l16 & 7)) * 8;

#define STAGE(b, kt)                                                       \
  do {                                                                     \
    const size_t ko = (size_t)(kt) * 64;                                   \
    gload_lds16(gA + ko,           &As[b][0][0] + t * 8);                  \
    gload_lds16(gA + ko + 32 * CC, &As[b][32][0] + t * 8);                 \
    gload_lds16(gB + ko,           &Bs[b][0][0] + t * 8);                  \
    gload_lds16(gB + ko + 32 * CC, &Bs[b][32][0] + t * 8);                 \
    gload_lds16(gB + ko + 64 * CC, &Bs[b][64][0] + t * 8);                 \
    gload_lds16(gB + ko + 96 * CC, &Bs[b][96][0] + t * 8);                 \
  } while (0)

  STAGE(0, 0);
  for (int kt = 0; kt < 16; ++kt) {
    const int cur = kt & 1;
    if (kt < 15) {
      STAGE(cur ^ 1, kt + 1);
      asm volatile("s_waitcnt vmcnt(6)" ::: "memory");
    } else {
      asm volatile("s_waitcnt vmcnt(0)" ::: "memory");
    }
    __builtin_amdgcn_s_barrier();
    asm volatile("" ::: "memory");
    bf16x8 af[2][2], bfr[4][2];
#pragma unroll
    for (int i = 0; i < 2; ++i) {
      af[i][0] = *(const bf16x8*)&As[cur][wm + i * 16 + l16][sw0];
      af[i][1] = *(const bf16x8*)&As[cur][wm + i * 16 + l16][sw1];
    }
#pragma unroll
    for (int j = 0; j < 4; ++j) {
      bfr[j][0] = *(const bf16x8*)&Bs[cur][wn + j * 16 + l16][sw0];
      bfr[j][1] = *(const bf16x8*)&Bs[cur][wn + j * 16 + l16][sw1];
    }
    __builtin_amdgcn_s_setprio(1);
#pragma unroll
    for (int i = 0; i < 2; ++i)
#pragma unroll
      for (int j = 0; j < 4; ++j) {
        acc[i][j] = __builtin_amdgcn_mfma_f32_16x16x32_bf16(af[i][0], bfr[j][0], acc[i][j], 0, 0, 0);
        acc[i][j] = __builtin_amdgcn_mfma_f32_16x16x32_bf16(af[i][1], bfr[j][1], acc[i][j], 0, 0, 0);
      }
    __builtin_amdgcn_s_setprio(0);
    asm volatile("" ::: "memory");
    __builtin_amdgcn_s_barrier();
    asm volatile("" ::: "memory");
  }
#undef STAGE

#pragma unroll
  for (int i = 0; i < 2; i++)
#pragma unroll
    for (int r = 0; r < 4; r++) {
      const int m = mBase + wm + i * 16 + quad * 4 + r;
#pragma unroll
      for (int j = 0; j < 4; j++) {
        const int n = nBase + wn + j * 16 + l16;
        out[(size_t)m * CC + n] = acc[i][j][r] + bias[n];
      }
    }
}

// ---------------------------------------------------------------------------
// R27 attn: R26 + K/V staging via gload_lds (pre-swizzled source, linear
// dest). One barrier/iter; vmcnt(0) ahead of it (loads have a full
// iteration of cover). Read side identical to R26.
// ---------------------------------------------------------------------------
__global__ __launch_bounds__(512, 4) void attn_mfma(
    const unsigned short* __restrict__ Q, const unsigned short* __restrict__ K,
    const unsigned short* __restrict__ Vt, unsigned short* __restrict__ y)
{
  __shared__ unsigned short Pt[128][64];     // 8 waves x 16-row P^T slots
  __shared__ unsigned short Ks[2][64][64];
  __shared__ unsigned short Vts[2][64][64];

  const int t = threadIdx.x;
  const int a = blockIdx.x;        // 0..15
  const int bh = blockIdx.y;       // 0..31
  const int wave = t >> 6;         // 0..7
  const int lane = t & 63;
  const int l16 = lane & 15;
  const int quad = lane >> 4;
  const int k7 = l16 & 7;          // read-side swizzle key (row&7 == l16&7)

  const size_t base = (size_t)bh * TT * HDD;
  const int qtL = a, qtH = 31 - a;
  const bool isHi = wave >= 4;
  const int myQt = isHi ? qtH : qtL;
  const int myQBase = (isHi ? qtH : qtL) * 64;
  const int rowInTile = (wave & 3) * 16 + l16;   // this lane's q-row (0..63)

  // Q fragments: direct global->reg, coalesced (2KB contiguous per wave)
  const unsigned short* qrow = Q + base + (size_t)(myQBase + rowInTile) * HDD + quad * 8;
  bf16x8 qf0 = *(const bf16x8*)(qrow);
  bf16x8 qf1 = *(const bf16x8*)(qrow + 32);

  unsigned short (*Ptw)[64] = (unsigned short (*)[64])&Pt[wave * 16];

  // K/V staging via gload_lds: LDS dest LINEAR (+t*8), global source chunk
  // pre-swizzled by row&7 -> phys chunk c holds logical c^(row&7) (== R26).
  const int sr = t >> 3;                         // row 0..63
  const unsigned short* kbaseS = K + base + (size_t)sr * HDD + ((t & 7) ^ (sr & 7)) * 8;
  const unsigned short* vbaseS = Vt + base + (size_t)sr * TT + ((t & 7) ^ (sr & 7)) * 8;
  unsigned short* kdst = &Ks[0][0][0] + t * 8;   // buf stride 64*64 shorts
  unsigned short* vdst = &Vts[0][0][0] + t * 8;

  float lsum = 0.f;
  f32x4 Ofr[4];
#pragma unroll
  for (int dt = 0; dt < 4; dt++) Ofr[dt] = (f32x4){0.f, 0.f, 0.f, 0.f};

  // prologue: stage tile 0 into buf 0
  gload_lds16(kbaseS, kdst);
  gload_lds16(vbaseS, vdst);

  for (int kt = 0; kt <= qtH; kt++) {
    const int buf = kt & 1;
    asm volatile("s_waitcnt vmcnt(0)" ::: "memory");
    __syncthreads();  // ONLY barrier: tile kt committed; prior-buf readers done
    if (kt < qtH) {   // stage kt+1 into buf^1 (WAR closed by the barrier above)
      gload_lds16(kbaseS + (size_t)(kt + 1) * 64 * HDD, kdst + (buf ^ 1) * 4096);
      gload_lds16(vbaseS + (size_t)(kt + 1) * 64,       vdst + (buf ^ 1) * 4096);
    }
    if (kt <= myQt) {
      // S^T = K Q^T for this wave's tile
      f32x4 St[4];
#pragma unroll
      for (int ct = 0; ct < 4; ct++) {
        bf16x8 a0 = *(const bf16x8*)&Ks[buf][ct * 16 + l16][(quad ^ k7) * 8];
        bf16x8 a1 = *(const bf16x8*)&Ks[buf][ct * 16 + l16][((4 + quad) ^ k7) * 8];
        f32x4 s = (f32x4){0.f, 0.f, 0.f, 0.f};
        s = __builtin_amdgcn_mfma_f32_16x16x32_bf16(a0, qf0, s, 0, 0, 0);
        s = __builtin_amdgcn_mfma_f32_16x16x32_bf16(a1, qf1, s, 0, 0, 0);
        St[ct] = s;
      }
      // softmax (mask only on the diagonal iteration — wave-uniform branch)
      // Pt write: logical chunk = 2*ct + (quad>>1), in-chunk off (quad&1)*4
      if (kt == myQt) {
#pragma unroll
        for (int ct = 0; ct < 4; ct++) {
          float p[4];
#pragma unroll
          for (int r = 0; r < 4; r++) {
            float pv = fexp2(St[ct][r]);
            if (ct * 16 + quad * 4 + r > rowInTile) pv = 0.f;
            p[r] = pv;
          }
          lsum += (p[0] + p[1]) + (p[2] + p[3]);
          uint2 pk = {pk_trunc(p[0], p[1]), pk_trunc(p[2], p[3])};
          *(uint2*)&Ptw[l16][((2 * ct + (quad >> 1)) ^ k7) * 8 + (quad & 1) * 4] = pk;
        }
      } else {
#pragma unroll
        for (int ct = 0; ct < 4; ct++) {
          float p[4];
#pragma unroll
          for (int r = 0; r < 4; r++) p[r] = fexp2(St[ct][r]);
          lsum += (p[0] + p[1]) + (p[2] + p[3]);
          uint2 pk = {pk_trunc(p[0], p[1]), pk_trunc(p[2], p[3])};
          *(uint2*)&Ptw[l16][((2 * ct + (quad >> 1)) ^ k7) * 8 + (quad & 1) * 4] = pk;
        }
      }
      // O += P V (Ptw wave-private: in-wave lgkmcnt ordering, no barrier)
      bf16x8 pa0 = *(const bf16x8*)&Ptw[l16][(quad ^ k7) * 8];
      bf16x8 pa1 = *(const bf16x8*)&Ptw[l16][((4 + quad) ^ k7) * 8];
#pragma unroll
      for (int dt = 0; dt < 4; dt++) {
        bf16x8 vb0 = *(const bf16x8*)&Vts[buf][dt * 16 + l16][(quad ^ k7) * 8];
        bf16x8 vb1 = *(const bf16x8*)&Vts[buf][dt * 16 + l16][((4 + quad) ^ k7) * 8];
        Ofr[dt] = __builtin_amdgcn_mfma_f32_16x16x32_bf16(pa0, vb0, Ofr[dt], 0, 0, 0);
        Ofr[dt] = __builtin_amdgcn_mfma_f32_16x16x32_bf16(pa1, vb1, Ofr[dt], 0, 0, 0);
      }
    }
    // no trailing barrier: next iter waits vmcnt(0) then barriers
  }

  // deferred cross-quad l reduction
  lsum += __shfl_xor(lsum, 16, 64);
  lsum += __shfl_xor(lsum, 32, 64);

  const int b = bh >> 4, h = bh & 15;
  float lRow[4];
#pragma unroll
  for (int r = 0; r < 4; r++) lRow[r] = __shfl(lsum, quad * 4 + r, 16);
#pragma unroll
  for (int r = 0; r < 4; r++) {
    const int q = myQBase + (wave & 3) * 16 + quad * 4 + r;
    const float inv = 1.0f / lRow[r];
    unsigned short* yp = y + ((size_t)(b * TT + q)) * CC + h * 64 + l16;
#pragma unroll
    for (int dt = 0; dt < 4; dt++) yp[dt * 16] = f2bf(Ofr[dt][r] * inv);
  }
}

extern "C" void kernel_launch(void* const* d_in, const int* in_sizes, int n_in,
                              void* d_out, int out_size, void* d_ws, size_t ws_size,
                              hipStream_t stream) {
  const float* x  = (const float*)d_in[0];
  const float* Wq = (const float*)d_in[1];
  const float* bq = (const float*)d_in[2];
  const float* Wk = (const float*)d_in[3];
  const float* bk = (const float*)d_in[4];
  const float* Wv = (const float*)d_in[5];
  const float* bv = (const float*)d_in[6];
  const float* Wp = (const float*)d_in[7];
  const float* bp = (const float*)d_in[8];

  const size_t M4 = 4194304, M1 = 1048576;
  unsigned short* xb   = (unsigned short*)d_ws;  // 4M
  unsigned short* wqb  = xb + M4;                // wq,wk,wv,wp contiguous
  unsigned short* wpb  = wqb + 3 * M1;
  unsigned short* wsQ  = wpb + M1;               // [B,H,T,HD] (pre-scaled)
  unsigned short* wsK  = wsQ + M4;               // [B,H,T,HD]
  unsigned short* wsVt = wsK + M4;               // [B,H,HD,T]
  unsigned short* yb   = wsVt + M4;              // [B,T,C] bf16

  convert_all<<<4096, 256, 0, stream>>>(x, Wq, Wk, Wv, Wp, xb);
  gemm_mfma<<<dim3(32, 24), 256, 0, stream>>>(xb, wqb, bq, bk, bv,
                                              wsQ, wsK, wsVt);
  attn_mfma<<<dim3(16, BB * HH), 512, 0, stream>>>(wsQ, wsK, wsVt, yb);
  gemm_proj<<<dim3(64, 8), 256, 0, stream>>>(yb, wpb, bp, (float*)d_out);
}

// Round 16
// 177.910 us; speedup vs baseline: 1.0210x; 1.0210x over previous
//
#include <hip/hip_runtime.h>
#include <hip/hip_bf16.h>

#define BB 2
#define TT 2048
#define CC 1024
#define HH 16
#define HDD 64

typedef __attribute__((ext_vector_type(8))) short bf16x8;
typedef __attribute__((ext_vector_type(4))) float f32x4;

static __device__ __forceinline__ unsigned short f2bf(float f) {
  union { float f; unsigned u; } v; v.f = f;
  unsigned r = v.u + 0x7fffu + ((v.u >> 16) & 1u);  // RNE
  return (unsigned short)(r >> 16);
}

static __device__ __forceinline__ unsigned fbits(float f) {
  union { float f; unsigned u; } v; v.f = f; return v.u;
}

// pack two fp32 -> two bf16 (truncate) in ONE v_perm_b32
static __device__ __forceinline__ unsigned pk_trunc(float lo, float hi) {
  return __builtin_amdgcn_perm(fbits(hi), fbits(lo), 0x07060302u);
}

// raw v_exp_f32 (args bounded; skips OCML range/subnormal fixup)
static __device__ __forceinline__ float fexp2(float x) {
#if __has_builtin(__builtin_amdgcn_exp2f)
  return __builtin_amdgcn_exp2f(x);
#else
  return exp2f(x);
#endif
}

static __device__ __forceinline__ void gload_lds16(const unsigned short* g, unsigned short* l) {
  __builtin_amdgcn_global_load_lds((const __attribute__((address_space(1))) void*)g,
                                   (__attribute__((address_space(3))) void*)l, 16, 0, 0);
}

// fp32 -> bf16 for x (4M), Wq,Wk,Wv,Wp (1M each), into contiguous dst.
__global__ __launch_bounds__(256) void convert_all(
    const float* __restrict__ x, const float* __restrict__ Wq,
    const float* __restrict__ Wk, const float* __restrict__ Wv,
    const float* __restrict__ Wp, unsigned short* __restrict__ dst)
{
  const size_t M4 = 4194304, M1 = 1048576;
  const size_t e = ((size_t)blockIdx.x * 256 + threadIdx.x) * 8;
  const float* src; size_t off;
  if (e < M4)            { src = x;  off = e; }
  else if (e < M4 + M1)  { src = Wq; off = e - M4; }
  else if (e < M4 + 2*M1){ src = Wk; off = e - M4 - M1; }
  else if (e < M4 + 3*M1){ src = Wv; off = e - M4 - 2*M1; }
  else                   { src = Wp; off = e - M4 - 3*M1; }
  float4 a = *(const float4*)(src + off);
  float4 c = *(const float4*)(src + off + 4);
  unsigned short buf[8] = {f2bf(a.x), f2bf(a.y), f2bf(a.z), f2bf(a.w),
                           f2bf(c.x), f2bf(c.y), f2bf(c.z), f2bf(c.w)};
  *(uint4*)(dst + e) = *(const uint4*)buf;
}

// ---------------------------------------------------------------------------
// R28 = R26 restored (best measured: 178.2us). R27's gload_lds attn staging
// regressed (+3.4us): the reg round-trip IS a T14 issue-early/write-late
// split (loads issue post-barrier, LDS writes commit next iteration under
// full compute cover), which beats LDS-DMA when idle waves give vmcnt(0)
// no cover. Composition final:
//  - QKV: R17 128x128 tri-buffer, counted vmcnt (2-phase floor, 42.4us)
//  - proj: R22 64x128 BK=64 dbuf (16 MFMA/interval)
//  - attn: R26 far-paired 8-wave split + XOR chunk-swizzle (conflicts -> 0)
// ---------------------------------------------------------------------------

// bf16 MFMA GEMM for fused QKV. grid (32,24), 256 threads. [R17 exact]
__global__ __launch_bounds__(256) void gemm_mfma(
    const unsigned short* __restrict__ A, const unsigned short* __restrict__ W,
    const float* __restrict__ b0, const float* __restrict__ b1, const float* __restrict__ b2,
    unsigned short* __restrict__ oQ, unsigned short* __restrict__ oK,
    unsigned short* __restrict__ oVt)
{
  __shared__ unsigned short As[3][128][32];
  __shared__ unsigned short Bs[3][128][32];
  const int t = threadIdx.x;
  const int wv = __builtin_amdgcn_readfirstlane(t >> 6);
  const int ln = t & 63;
  const int l16 = ln & 15;
  const int quad = ln >> 4;
  const int mBase = blockIdx.x * 128;
  const int nBase = blockIdx.y * 128;
  const int wm = (wv >> 1) * 64, wn = (wv & 1) * 64;

  f32x4 acc[4][4];
#pragma unroll
  for (int i = 0; i < 4; i++)
#pragma unroll
    for (int j = 0; j < 4; j++) acc[i][j] = (f32x4){0.f, 0.f, 0.f, 0.f};

  const int rloc = t >> 2;
  const int csrc = ((t & 3) ^ ((t >> 3) & 3)) * 8;
  const unsigned short* gA = A + (size_t)(mBase + rloc) * CC + csrc;
  const unsigned short* gB = W + (size_t)(nBase + rloc) * CC + csrc;
  const int sw = (quad ^ ((l16 >> 1) & 3)) * 8;

#define STAGE(b, kt)                                                       \
  do {                                                                     \
    const size_t ko = (size_t)(kt) * 32;                                   \
    gload_lds16(gA + ko,           &As[b][0][0] + t * 8);                  \
    gload_lds16(gA + ko + 64 * CC, &As[b][64][0] + t * 8);                 \
    gload_lds16(gB + ko,           &Bs[b][0][0] + t * 8);                  \
    gload_lds16(gB + ko + 64 * CC, &Bs[b][64][0] + t * 8);                 \
  } while (0)

  STAGE(0, 0);
  STAGE(1, 1);
  int cur = 0, nxt2 = 2;
  for (int kt = 0; kt < 32; ++kt) {
    if (kt < 30) {
      STAGE(nxt2, kt + 2);
      asm volatile("s_waitcnt vmcnt(8)" ::: "memory");
    } else if (kt == 30) {
      asm volatile("s_waitcnt vmcnt(4)" ::: "memory");
    } else {
      asm volatile("s_waitcnt vmcnt(0)" ::: "memory");
    }
    __builtin_amdgcn_s_barrier();
    asm volatile("" ::: "memory");
    bf16x8 af[4], bfr[4];
#pragma unroll
    for (int i = 0; i < 4; ++i) af[i] = *(const bf16x8*)&As[cur][wm + i * 16 + l16][sw];
#pragma unroll
    for (int j = 0; j < 4; ++j) bfr[j] = *(const bf16x8*)&Bs[cur][wn + j * 16 + l16][sw];
    __builtin_amdgcn_s_setprio(1);
#pragma unroll
    for (int i = 0; i < 4; ++i)
#pragma unroll
      for (int j = 0; j < 4; ++j)
        acc[i][j] = __builtin_amdgcn_mfma_f32_16x16x32_bf16(af[i], bfr[j], acc[i][j], 0, 0, 0);
    __builtin_amdgcn_s_setprio(0);
    asm volatile("" ::: "memory");
    __builtin_amdgcn_s_barrier();
    asm volatile("" ::: "memory");
    cur = (cur == 2) ? 0 : cur + 1;
    nxt2 = (nxt2 == 2) ? 0 : nxt2 + 1;
  }
#undef STAGE

  const int which = nBase >> 10;
  const float* bias = which == 0 ? b0 : (which == 1 ? b1 : b2);
  unsigned short* dst = which == 0 ? oQ : (which == 1 ? oK : oVt);
  const float scl = which == 0 ? 0.1803368801f : 1.0f;  // 0.125*log2(e) on Q
#pragma unroll
  for (int i = 0; i < 4; i++)
#pragma unroll
    for (int r = 0; r < 4; r++) {
      const int m = mBase + wm + i * 16 + quad * 4 + r;
      const int b = m >> 11, tp = m & 2047;
#pragma unroll
      for (int j = 0; j < 4; j++) {
        const int n = nBase + wn + j * 16 + l16;
        const int nl = n & 1023, h = nl >> 6, d = nl & 63;
        const unsigned short v = f2bf((acc[i][j][r] + bias[nl]) * scl);
        if (which < 2) dst[((size_t)(b * HH + h) * TT + tp) * HDD + d] = v;
        else           dst[((size_t)(b * HH + h) * HDD + d) * TT + tp] = v;
      }
    }
}

// Output projection: 64x128 tile, BK=64 dbuf (16 MFMA/interval), vmcnt(6),
// 256 threads, grid (64,8) = 512 blocks = 2 blocks/CU. [R22 exact]
__global__ __launch_bounds__(256) void gemm_proj(
    const unsigned short* __restrict__ A, const unsigned short* __restrict__ W,
    const float* __restrict__ bias, float* __restrict__ out)
{
  __shared__ unsigned short As[2][64][64];
  __shared__ unsigned short Bs[2][128][64];
  const int t = threadIdx.x;
  const int wv = __builtin_amdgcn_readfirstlane(t >> 6);
  const int ln = t & 63;
  const int l16 = ln & 15;
  const int quad = ln >> 4;
  const int mBase = blockIdx.x * 64;
  const int nBase = blockIdx.y * 128;
  const int wm = (wv >> 1) * 32, wn = (wv & 1) * 64;

  f32x4 acc[2][4];
#pragma unroll
  for (int i = 0; i < 2; i++)
#pragma unroll
    for (int j = 0; j < 4; j++) acc[i][j] = (f32x4){0.f, 0.f, 0.f, 0.f};

  const int srow = t >> 3;                         // 0..31
  const int schunk = ((t & 7) ^ (srow & 7)) * 8;
  const unsigned short* gA = A + (size_t)(mBase + srow) * CC + schunk;
  const unsigned short* gB = W + (size_t)(nBase + srow) * CC + schunk;
  const int sw0 = ((0 + quad) ^ (l16 & 7)) * 8;
  const int sw1 = ((4 + quad) ^ (l16 & 7)) * 8;

#define STAGE(b, kt)                                                       \
  do {                                                                     \
    const size_t ko = (size_t)(kt) * 64;                                   \
    gload_lds16(gA + ko,           &As[b][0][0] + t * 8);                  \
    gload_lds16(gA + ko + 32 * CC, &As[b][32][0] + t * 8);                 \
    gload_lds16(gB + ko,           &Bs[b][0][0] + t * 8);                  \
    gload_lds16(gB + ko + 32 * CC, &Bs[b][32][0] + t * 8);                 \
    gload_lds16(gB + ko + 64 * CC, &Bs[b][64][0] + t * 8);                 \
    gload_lds16(gB + ko + 96 * CC, &Bs[b][96][0] + t * 8);                 \
  } while (0)

  STAGE(0, 0);
  for (int kt = 0; kt < 16; ++kt) {
    const int cur = kt & 1;
    if (kt < 15) {
      STAGE(cur ^ 1, kt + 1);
      asm volatile("s_waitcnt vmcnt(6)" ::: "memory");
    } else {
      asm volatile("s_waitcnt vmcnt(0)" ::: "memory");
    }
    __builtin_amdgcn_s_barrier();
    asm volatile("" ::: "memory");
    bf16x8 af[2][2], bfr[4][2];
#pragma unroll
    for (int i = 0; i < 2; ++i) {
      af[i][0] = *(const bf16x8*)&As[cur][wm + i * 16 + l16][sw0];
      af[i][1] = *(const bf16x8*)&As[cur][wm + i * 16 + l16][sw1];
    }
#pragma unroll
    for (int j = 0; j < 4; ++j) {
      bfr[j][0] = *(const bf16x8*)&Bs[cur][wn + j * 16 + l16][sw0];
      bfr[j][1] = *(const bf16x8*)&Bs[cur][wn + j * 16 + l16][sw1];
    }
    __builtin_amdgcn_s_setprio(1);
#pragma unroll
    for (int i = 0; i < 2; ++i)
#pragma unroll
      for (int j = 0; j < 4; ++j) {
        acc[i][j] = __builtin_amdgcn_mfma_f32_16x16x32_bf16(af[i][0], bfr[j][0], acc[i][j], 0, 0, 0);
        acc[i][j] = __builtin_amdgcn_mfma_f32_16x16x32_bf16(af[i][1], bfr[j][1], acc[i][j], 0, 0, 0);
      }
    __builtin_amdgcn_s_setprio(0);
    asm volatile("" ::: "memory");
    __builtin_amdgcn_s_barrier();
    asm volatile("" ::: "memory");
  }
#undef STAGE

#pragma unroll
  for (int i = 0; i < 2; i++)
#pragma unroll
    for (int r = 0; r < 4; r++) {
      const int m = mBase + wm + i * 16 + quad * 4 + r;
#pragma unroll
      for (int j = 0; j < 4; j++) {
        const int n = nBase + wn + j * 16 + l16;
        out[(size_t)m * CC + n] = acc[i][j][r] + bias[n];
      }
    }
}

// ---------------------------------------------------------------------------
// R26 attn exact: far-paired 8-wave tile-split + XOR chunk-swizzled LDS.
// Reg-staged K/V (issue-early/write-late split — beats gload_lds here).
// ---------------------------------------------------------------------------
__global__ __launch_bounds__(512, 4) void attn_mfma(
    const unsigned short* __restrict__ Q, const unsigned short* __restrict__ K,
    const unsigned short* __restrict__ Vt, unsigned short* __restrict__ y)
{
  __shared__ unsigned short Pt[128][64];     // 8 waves x 16-row P^T slots
  __shared__ unsigned short Ks[2][64][64];
  __shared__ unsigned short Vts[2][64][64];

  const int t = threadIdx.x;
  const int a = blockIdx.x;        // 0..15
  const int bh = blockIdx.y;       // 0..31
  const int wave = t >> 6;         // 0..7
  const int lane = t & 63;
  const int l16 = lane & 15;
  const int quad = lane >> 4;
  const int k7 = l16 & 7;          // read-side swizzle key (row&7 == l16&7)

  const size_t base = (size_t)bh * TT * HDD;
  const int qtL = a, qtH = 31 - a;
  const bool isHi = wave >= 4;
  const int myQt = isHi ? qtH : qtL;
  const int myQBase = (isHi ? qtH : qtL) * 64;
  const int rowInTile = (wave & 3) * 16 + l16;   // this lane's q-row (0..63)

  // Q fragments: direct global->reg, coalesced (2KB contiguous per wave)
  const unsigned short* qrow = Q + base + (size_t)(myQBase + rowInTile) * HDD + quad * 8;
  bf16x8 qf0 = *(const bf16x8*)(qrow);
  bf16x8 qf1 = *(const bf16x8*)(qrow + 32);

  unsigned short (*Ptw)[64] = (unsigned short (*)[64])&Pt[wave * 16];

  // K/V staging: 512 threads, 1 uint4 each; store chunk swizzled by row&7
  const int sr = t >> 3;                         // row 0..63
  const int scp = ((t & 7) ^ (sr & 7)) * 8;      // phys chunk col (shorts)
  const unsigned short* kbase = K + base + (size_t)sr * HDD + (t & 7) * 8;
  const unsigned short* vbase = Vt + base + (size_t)sr * TT + (t & 7) * 8;
  uint4 kr = *(const uint4*)(kbase);
  uint4 vr = *(const uint4*)(vbase);

  float lsum = 0.f;
  f32x4 Ofr[4];
#pragma unroll
  for (int dt = 0; dt < 4; dt++) Ofr[dt] = (f32x4){0.f, 0.f, 0.f, 0.f};

  for (int kt = 0; kt <= qtH; kt++) {
    const int buf = kt & 1;
    *(uint4*)&Ks[buf][sr][scp]  = kr;
    *(uint4*)&Vts[buf][sr][scp] = vr;
    __syncthreads();  // ONLY barrier: commits visible; prior-buf readers done
    if (kt < qtH) {
      kr = *(const uint4*)(kbase + (size_t)(kt + 1) * 64 * HDD);
      vr = *(const uint4*)(vbase + (kt + 1) * 64);
    }
    if (kt <= myQt) {
      // S^T = K Q^T for this wave's tile
      f32x4 St[4];
#pragma unroll
      for (int ct = 0; ct < 4; ct++) {
        bf16x8 a0 = *(const bf16x8*)&Ks[buf][ct * 16 + l16][(quad ^ k7) * 8];
        bf16x8 a1 = *(const bf16x8*)&Ks[buf][ct * 16 + l16][((4 + quad) ^ k7) * 8];
        f32x4 s = (f32x4){0.f, 0.f, 0.f, 0.f};
        s = __builtin_amdgcn_mfma_f32_16x16x32_bf16(a0, qf0, s, 0, 0, 0);
        s = __builtin_amdgcn_mfma_f32_16x16x32_bf16(a1, qf1, s, 0, 0, 0);
        St[ct] = s;
      }
      // softmax (mask only on the diagonal iteration — wave-uniform branch)
      // Pt write: logical chunk = 2*ct + (quad>>1), in-chunk off (quad&1)*4
      if (kt == myQt) {
#pragma unroll
        for (int ct = 0; ct < 4; ct++) {
          float p[4];
#pragma unroll
          for (int r = 0; r < 4; r++) {
            float pv = fexp2(St[ct][r]);
            if (ct * 16 + quad * 4 + r > rowInTile) pv = 0.f;
            p[r] = pv;
          }
          lsum += (p[0] + p[1]) + (p[2] + p[3]);
          uint2 pk = {pk_trunc(p[0], p[1]), pk_trunc(p[2], p[3])};
          *(uint2*)&Ptw[l16][((2 * ct + (quad >> 1)) ^ k7) * 8 + (quad & 1) * 4] = pk;
        }
      } else {
#pragma unroll
        for (int ct = 0; ct < 4; ct++) {
          float p[4];
#pragma unroll
          for (int r = 0; r < 4; r++) p[r] = fexp2(St[ct][r]);
          lsum += (p[0] + p[1]) + (p[2] + p[3]);
          uint2 pk = {pk_trunc(p[0], p[1]), pk_trunc(p[2], p[3])};
          *(uint2*)&Ptw[l16][((2 * ct + (quad >> 1)) ^ k7) * 8 + (quad & 1) * 4] = pk;
        }
      }
      // O += P V (Ptw wave-private: in-wave lgkmcnt ordering, no barrier)
      bf16x8 pa0 = *(const bf16x8*)&Ptw[l16][(quad ^ k7) * 8];
      bf16x8 pa1 = *(const bf16x8*)&Ptw[l16][((4 + quad) ^ k7) * 8];
#pragma unroll
      for (int dt = 0; dt < 4; dt++) {
        bf16x8 vb0 = *(const bf16x8*)&Vts[buf][dt * 16 + l16][(quad ^ k7) * 8];
        bf16x8 vb1 = *(const bf16x8*)&Vts[buf][dt * 16 + l16][((4 + quad) ^ k7) * 8];
        Ofr[dt] = __builtin_amdgcn_mfma_f32_16x16x32_bf16(pa0, vb0, Ofr[dt], 0, 0, 0);
        Ofr[dt] = __builtin_amdgcn_mfma_f32_16x16x32_bf16(pa1, vb1, Ofr[dt], 0, 0, 0);
      }
    }
    // no trailing barrier: next iter commits the OTHER buffer
  }

  // deferred cross-quad l reduction
  lsum += __shfl_xor(lsum, 16, 64);
  lsum += __shfl_xor(lsum, 32, 64);

  const int b = bh >> 4, h = bh & 15;
  float lRow[4];
#pragma unroll
  for (int r = 0; r < 4; r++) lRow[r] = __shfl(lsum, quad * 4 + r, 16);
#pragma unroll
  for (int r = 0; r < 4; r++) {
    const int q = myQBase + (wave & 3) * 16 + quad * 4 + r;
    const float inv = 1.0f / lRow[r];
    unsigned short* yp = y + ((size_t)(b * TT + q)) * CC + h * 64 + l16;
#pragma unroll
    for (int dt = 0; dt < 4; dt++) yp[dt * 16] = f2bf(Ofr[dt][r] * inv);
  }
}

extern "C" void kernel_launch(void* const* d_in, const int* in_sizes, int n_in,
                              void* d_out, int out_size, void* d_ws, size_t ws_size,
                              hipStream_t stream) {
  const float* x  = (const float*)d_in[0];
  const float* Wq = (const float*)d_in[1];
  const float* bq = (const float*)d_in[2];
  const float* Wk = (const float*)d_in[3];
  const float* bk = (const float*)d_in[4];
  const float* Wv = (const float*)d_in[5];
  const float* bv = (const float*)d_in[6];
  const float* Wp = (const float*)d_in[7];
  const float* bp = (const float*)d_in[8];

  const size_t M4 = 4194304, M1 = 1048576;
  unsigned short* xb   = (unsigned short*)d_ws;  // 4M
  unsigned short* wqb  = xb + M4;                // wq,wk,wv,wp contiguous
  unsigned short* wpb  = wqb + 3 * M1;
  unsigned short* wsQ  = wpb + M1;               // [B,H,T,HD] (pre-scaled)
  unsigned short* wsK  = wsQ + M4;               // [B,H,T,HD]
  unsigned short* wsVt = wsK + M4;               // [B,H,HD,T]
  unsigned short* yb   = wsVt + M4;              // [B,T,C] bf16

  convert_all<<<4096, 256, 0, stream>>>(x, Wq, Wk, Wv, Wp, xb);
  gemm_mfma<<<dim3(32, 24), 256, 0, stream>>>(xb, wqb, bq, bk, bv,
                                              wsQ, wsK, wsVt);
  attn_mfma<<<dim3(16, BB * HH), 512, 0, stream>>>(wsQ, wsK, wsVt, yb);
  gemm_proj<<<dim3(64, 8), 256, 0, stream>>>(yb, wpb, bp, (float*)d_out);
}